// Round 6
// baseline (300.794 us; speedup 1.0000x reference)
//
#include <hip/hip_runtime.h>
#include <hip/hip_bf16.h>

#define BATCH 256
#define SEQ   512
#define NT    64
#define PCH   8     // chunks per sequence
#define CLEN  64    // steps per chunk (last chunk: 63)
#define PITCH 68    // ldsT pitch in halves (final transpose only)

typedef short bf16x8  __attribute__((ext_vector_type(8)));
typedef float f32x16  __attribute__((ext_vector_type(16)));
typedef float f32x4   __attribute__((ext_vector_type(4)));

#define MEMBAR() __asm__ __volatile__("" ::: "memory")

static __device__ __forceinline__ short bf16_trunc(float v) {
    return (short)(__float_as_uint(v) >> 16);
}
static __device__ __forceinline__ unsigned pack_bf16_rn(float lo, float hi) {
    float2 f; f.x = lo; f.y = hi;
    __hip_bfloat162 hh = __float22bfloat162_rn(f);   // v_cvt_pk_bf16_f32
    unsigned u; __builtin_memcpy(&u, &hh, 4);
    return u;
}

// ---------------------------------------------------------------------------
// Fused kernel: block (c,b) = 128 threads = 2 waves; wave w owns columns
// n in [32w, 32w+32) of the chunk product (columns are independent -> no
// inter-wave traffic). Register-resident chain: C accs feed next step's B;
// row permutation rho(h,j)=(j&3)+8*(j>>2)+4h pre-folded into A (proven r4/r5).
// Last-finishing block per batch runs the 8-step combine (no 2nd kernel).
// ---------------------------------------------------------------------------
__global__ __launch_bounds__(128, 4) void crf_fused_kernel(
    const float* __restrict__ emissions,   // (B,S,T)
    const int*   __restrict__ tags,        // (B,S)
    const int*   __restrict__ mask,        // (B,S)
    const float* __restrict__ start_tr,    // (T)
    const float* __restrict__ end_tr,      // (T)
    const float* __restrict__ trans,       // (T,T)
    unsigned short* __restrict__ mats,     // (B,PCH,64,64) bf16: [n][k] = M[k][n]
    float* __restrict__ ws_head,           // [0]=sum, [1]=cnt   (pre-zeroed)
    unsigned* __restrict__ done,           // (B) chunk-done counters (pre-zeroed)
    float* __restrict__ score_part,        // (B,PCH)
    int*   __restrict__ mcnt_part,         // (B,PCH)
    float* __restrict__ out)
{
    __shared__ __align__(16) unsigned char smem[CLEN * NT * 4];  // 16 KB
    __shared__ unsigned is_last;
    float (*w_lds)[NT] = (float (*)[NT])smem;
    unsigned short* ldsT = (unsigned short*)smem;   // overlay after main loop
    float* r_lds = (float*)smem;                    // overlay during combine

    const int c    = blockIdx.x;
    const int b    = blockIdx.y;
    const int tid  = threadIdx.x;
    const int lane = tid & 63;
    const int wave = tid >> 6;
    const int h    = lane >> 5;
    const int ml   = lane & 31;

    const int s0 = c * CLEN;
    int L = (SEQ - 1) - s0; if (L > CLEN) L = CLEN;

    const float* em_b = emissions + (size_t)b * SEQ * NT;
    const int*   tg_b = tags + b * SEQ;
    const int*   mk_b = mask + b * SEQ;

    // stage w = exp(emissions) for steps s0+1 .. s0+L (both waves, coalesced)
    for (int i = tid; i < L * NT; i += 128)
        ((float*)smem)[i] = __expf(em_b[(size_t)(s0 + 1) * NT + i]);

    // ---- distributed numerator partial (wave 0; L <= 64 lanes cover it) ----
    if (wave == 0) {
        float np = 0.f;
        int   mc = 0;
        if (lane < L) {
            int s  = s0 + 1 + lane;
            int m  = mk_b[s];
            mc = m;
            int t  = tg_b[s];
            int tp = tg_b[s - 1];
            float v = trans[tp * NT + t] + em_b[(size_t)s * NT + t];
            np = m ? v : 0.f;
        }
        if (c == 0 && lane == 0) {
            int t0 = tg_b[0];
            np += start_tr[t0] + em_b[t0];
            mc += mk_b[0];
        }
#pragma unroll
        for (int d = 32; d; d >>= 1) {
            np += __shfl_xor(np, d);
            mc += __shfl_xor(mc, d);
        }
        if (lane == 0) {
            score_part[b * PCH + c] = np;
            mcnt_part[b * PCH + c]  = mc;
        }
    }

    // Permuted A (full matrix per wave): Af[mt][kk] slot (h,j) = Es[m][r],
    // Es = E^T * 2^-7, r = 32*(kk>>1) + 16*(kk&1) + (j&3) + 8*(j>>2) + 4h
    bf16x8 Af[2][4];
#pragma unroll
    for (int mt = 0; mt < 2; ++mt) {
        int m = mt * 32 + ml;
#pragma unroll
        for (int kk = 0; kk < 4; ++kk) {
            bf16x8 f;
#pragma unroll
            for (int j = 0; j < 8; ++j) {
                int r = 32 * (kk >> 1) + 16 * (kk & 1) + (j & 3) + 8 * (j >> 2) + 4 * h;
                f[j] = bf16_trunc(__expf(trans[r * NT + m]) * 0.0078125f);
            }
            Af[mt][kk] = f;
        }
    }

    // B := identity columns for this wave's n-range (permuted-B convention)
    union BU { unsigned u[4]; bf16x8 v; };
    BU Bv[4];
    const int n_own = wave * 32 + ml;
#pragma unroll
    for (int kk = 0; kk < 4; ++kk)
#pragma unroll
        for (int d = 0; d < 4; ++d) {
            int j0 = 2 * d;
            int r0 = 32 * (kk >> 1) + 16 * (kk & 1) + (j0 & 3) + 8 * (j0 >> 2) + 4 * h;
            unsigned lo = (r0     == n_own) ? 0x3f80u : 0u;
            unsigned hi = (r0 + 1 == n_own) ? 0x3f80u : 0u;
            Bv[kk].u[d] = lo | (hi << 16);
        }

    __syncthreads();  // w_lds ready

    for (int s = 0; s < L; ++s) {
        f32x4 wq0[4], wq1[4];
#pragma unroll
        for (int kk = 0; kk < 4; ++kk) {
            int base = 32 * (kk >> 1) + 16 * (kk & 1) + 4 * h;
            wq0[kk] = *(const f32x4*)&w_lds[s][base];
            wq1[kk] = *(const f32x4*)&w_lds[s][base + 8];
        }

        const f32x16 zf = {};
        f32x16 a0 = __builtin_amdgcn_mfma_f32_32x32x16_bf16(Af[0][0], Bv[0].v, zf, 0, 0, 0);
        a0 = __builtin_amdgcn_mfma_f32_32x32x16_bf16(Af[0][1], Bv[1].v, a0, 0, 0, 0);
        a0 = __builtin_amdgcn_mfma_f32_32x32x16_bf16(Af[0][2], Bv[2].v, a0, 0, 0, 0);
        a0 = __builtin_amdgcn_mfma_f32_32x32x16_bf16(Af[0][3], Bv[3].v, a0, 0, 0, 0);
        f32x16 a1 = __builtin_amdgcn_mfma_f32_32x32x16_bf16(Af[1][0], Bv[0].v, zf, 0, 0, 0);
        a1 = __builtin_amdgcn_mfma_f32_32x32x16_bf16(Af[1][1], Bv[1].v, a1, 0, 0, 0);
        a1 = __builtin_amdgcn_mfma_f32_32x32x16_bf16(Af[1][2], Bv[2].v, a1, 0, 0, 0);
        a1 = __builtin_amdgcn_mfma_f32_32x32x16_bf16(Af[1][3], Bv[3].v, a1, 0, 0, 0);

        // Repack: B-slot (kk,d) <- w[r]*C[r][n] pairs, packed bf16 cvt.
#pragma unroll
        for (int kk = 0; kk < 4; ++kk) {
            const int qo = 8 * (kk & 1);
#pragma unroll
            for (int d = 0; d < 4; ++d) {
                int j0 = 2 * d;
                float c0 = (kk < 2) ? a0[qo + j0]     : a1[qo + j0];
                float c1 = (kk < 2) ? a0[qo + j0 + 1] : a1[qo + j0 + 1];
                float w0 = (d < 2) ? wq0[kk][2 * (d & 1)]     : wq1[kk][2 * (d & 1)];
                float w1 = (d < 2) ? wq0[kk][2 * (d & 1) + 1] : wq1[kk][2 * (d & 1) + 1];
                Bv[kk].u[d] = pack_bf16_rn(c0 * w0, c1 * w1);
            }
        }
    }

    // Transpose through LDS (overlays w_lds; both waves done with it)
    __syncthreads();
#pragma unroll
    for (int kk = 0; kk < 4; ++kk)
#pragma unroll
        for (int d = 0; d < 4; ++d) {
            int j0 = 2 * d;
            int r0 = 32 * (kk >> 1) + 16 * (kk & 1) + (j0 & 3) + 8 * (j0 >> 2) + 4 * h;
            *(unsigned*)&ldsT[n_own * PITCH + r0] = Bv[kk].u[d];
        }
    __syncthreads();

    unsigned short* outp = mats + ((size_t)(b * PCH + c)) * 4096;
    for (int it = 0; it < 4; ++it) {
        int o = it * 1024 + tid * 8;       // half index in [0,4096)
        int n = o >> 6, k = o & 63;
        const uint2* p = (const uint2*)(ldsT + n * PITCH + k);
        uint2 x = p[0], y = p[1];
        uint4 q4; q4.x = x.x; q4.y = x.y; q4.z = y.x; q4.w = y.y;
        *(uint4*)(outp + o) = q4;
    }

    // ---- release + elect last block of this batch ----
    __threadfence();
    __syncthreads();
    if (tid == 0) {
        unsigned old = atomicAdd(&done[b], 1u);
        is_last = (old == PCH - 1) ? 1u : 0u;
    }
    __syncthreads();
    if (!is_last) return;
    __threadfence();   // acquire: all 8 chunk writes for batch b now visible
    if (wave != 0) return;

    // ================= combine (wave 0 of the last block) =================
    const int j = lane;
    const unsigned short* mb = mats + (size_t)b * PCH * 4096;

    float sp = (j < PCH) ? score_part[b * PCH + j] : 0.f;
    int   mp = (j < PCH) ? mcnt_part[b * PCH + j] : 0;

    float r = __expf(end_tr[j]);
    MEMBAR(); r_lds[j] = r; MEMBAR();
    int X = 0;

    uint4 buf[2][8];
#pragma unroll
    for (int u = 0; u < 8; ++u)
        buf[0][u] = *(const uint4*)(mb + (size_t)(PCH - 1) * 4096 + j * 64 + u * 8);

#pragma unroll
    for (int d = 32; d; d >>= 1) {
        sp += __shfl_xor(sp, d);
        mp += __shfl_xor(mp, d);
    }
    float score_num = sp + end_tr[tg_b[mp - 1]];

#pragma unroll
    for (int cc = PCH - 1; cc >= 0; --cc) {
        const int slot = (PCH - 1 - cc) & 1;
        if (cc > 0) {
#pragma unroll
            for (int u = 0; u < 8; ++u)
                buf[slot ^ 1][u] = *(const uint4*)(mb + (size_t)(cc - 1) * 4096 + j * 64 + u * 8);
        }
        float a0 = 0.f, a1 = 0.f, a2 = 0.f, a3 = 0.f;
#pragma unroll
        for (int u = 0; u < 8; ++u) {
            uint4 q = buf[slot][u];
            f32x4 ra = *(const f32x4*)&r_lds[u * 8];
            f32x4 rb = *(const f32x4*)&r_lds[u * 8 + 4];
            a0 = fmaf(ra[0], __uint_as_float(q.x << 16),         a0);
            a1 = fmaf(ra[1], __uint_as_float(q.x & 0xffff0000u), a1);
            a2 = fmaf(ra[2], __uint_as_float(q.y << 16),         a2);
            a3 = fmaf(ra[3], __uint_as_float(q.y & 0xffff0000u), a3);
            a0 = fmaf(rb[0], __uint_as_float(q.z << 16),         a0);
            a1 = fmaf(rb[1], __uint_as_float(q.z & 0xffff0000u), a1);
            a2 = fmaf(rb[2], __uint_as_float(q.w << 16),         a2);
            a3 = fmaf(rb[3], __uint_as_float(q.w & 0xffff0000u), a3);
        }
        float rn = (a0 + a1) + (a2 + a3);
        unsigned eb = (__builtin_amdgcn_readfirstlane((int)__float_as_uint(rn)) >> 23) & 0xffu;
        r = rn * __uint_as_float((254u - eb) << 23);   // * 2^(127-eb)
        X += (int)eb - 127;
        MEMBAR();
        r_lds[j] = r;
        MEMBAR();
    }

    float u0 = __expf(start_tr[j] + em_b[j]);
    float v = r * u0;
#pragma unroll
    for (int d = 32; d; d >>= 1) v += __shfl_xor(v, d);

    if (j == 0) {
        float denom = __logf(v) + (float)(X + 7 * (SEQ - 1)) * 0.6931471805599453f;
        float llh = denom - score_num;
        atomicAdd(&ws_head[0], llh * (1.0f / BATCH));
        __threadfence();
        unsigned old = atomicAdd((unsigned*)ws_head + 1, 1u);
        if (old == BATCH - 1) {
            __threadfence();
            out[0] = atomicAdd(&ws_head[0], 0.0f);
        }
    }
}

extern "C" void kernel_launch(void* const* d_in, const int* in_sizes, int n_in,
                              void* d_out, int out_size, void* d_ws, size_t ws_size,
                              hipStream_t stream) {
    const float* emissions = (const float*)d_in[0];
    const int*   tags      = (const int*)d_in[1];
    const int*   mask      = (const int*)d_in[2];
    const float* start_tr  = (const float*)d_in[3];
    const float* end_tr    = (const float*)d_in[4];
    const float* trans     = (const float*)d_in[5];

    float*    ws_head    = (float*)d_ws;                         // 8 B
    unsigned* done       = (unsigned*)((char*)d_ws + 64);        // 1 KB
    float*    score_part = (float*)((char*)d_ws + 4096);         // 8 KB
    int*      mcnt_part  = (int*)((char*)d_ws + 12288);          // 8 KB
    unsigned short* mats = (unsigned short*)((char*)d_ws + 32768); // 16 MB

    hipMemsetAsync(d_ws, 0, 4096, stream);   // zero ws_head + done counters
    crf_fused_kernel<<<dim3(PCH, BATCH), 128, 0, stream>>>(
        emissions, tags, mask, start_tr, end_tr, trans,
        mats, ws_head, done, score_part, mcnt_part, (float*)d_out);
}

// Round 7
// 233.488 us; speedup vs baseline: 1.2883x; 1.2883x over previous
//
#include <hip/hip_runtime.h>
#include <hip/hip_bf16.h>

#define BATCH 256
#define SEQ   512
#define NT    64
#define PCH   8     // chunks per sequence
#define CLEN  64    // steps per chunk (last chunk: 63)
#define PITCH 68    // ldsT pitch in halves (final transpose only)

typedef short bf16x8  __attribute__((ext_vector_type(8)));
typedef float f32x16  __attribute__((ext_vector_type(16)));
typedef float f32x4   __attribute__((ext_vector_type(4)));

#define MEMBAR() __asm__ __volatile__("" ::: "memory")

static __device__ __forceinline__ short bf16_trunc(float v) {
    return (short)(__float_as_uint(v) >> 16);
}
static __device__ __forceinline__ unsigned pack_bf16_rn(float lo, float hi) {
    float2 f; f.x = lo; f.y = hi;
    __hip_bfloat162 hh = __float22bfloat162_rn(f);   // v_cvt_pk_bf16_f32
    unsigned u; __builtin_memcpy(&u, &hh, 4);
    return u;
}

// ---------------------------------------------------------------------------
// Fused kernel, r4 shape: ONE wave per (batch, chunk) block; register-resident
// matrix chain (16 MFMA/step; C accs feed next B; row permutation
// rho(h,j)=(j&3)+8*(j>>2)+4h pre-folded into A — proven r4/r5/r6).
// Last-finishing block per batch runs the 8-step combine in-kernel (r6's
// proven election), deleting the 2nd dispatch and its ~70us residual.
// ---------------------------------------------------------------------------
__global__ __launch_bounds__(64, 2) void crf_fused_kernel(
    const float* __restrict__ emissions,   // (B,S,T)
    const int*   __restrict__ tags,        // (B,S)
    const int*   __restrict__ mask,        // (B,S)
    const float* __restrict__ start_tr,    // (T)
    const float* __restrict__ end_tr,      // (T)
    const float* __restrict__ trans,       // (T,T)
    unsigned short* __restrict__ mats,     // (B,PCH,64,64) bf16: [n][k] = M[k][n]
    float* __restrict__ ws_head,           // [0]=sum, [1]=cnt   (pre-zeroed)
    unsigned* __restrict__ done,           // (B) chunk-done counters (pre-zeroed)
    float* __restrict__ score_part,        // (B,PCH)
    int*   __restrict__ mcnt_part,         // (B,PCH)
    float* __restrict__ out)
{
    __shared__ __align__(16) unsigned char smem[CLEN * NT * 4];  // 16 KB
    float (*w_lds)[NT] = (float (*)[NT])smem;
    unsigned short* ldsT = (unsigned short*)smem;   // overlay after main loop
    float* r_lds = (float*)smem;                    // overlay during combine

    const int c    = blockIdx.x;
    const int b    = blockIdx.y;
    const int lane = threadIdx.x;
    const int h    = lane >> 5;
    const int ml   = lane & 31;

    const int s0 = c * CLEN;
    int L = (SEQ - 1) - s0; if (L > CLEN) L = CLEN;

    const float* em_b = emissions + (size_t)b * SEQ * NT;
    const int*   tg_b = tags + b * SEQ;
    const int*   mk_b = mask + b * SEQ;

    // stage w = exp(emissions) for steps s0+1 .. s0+L
    for (int s = 0; s < L; ++s)
        w_lds[s][lane] = __expf(em_b[(size_t)(s0 + 1 + s) * NT + lane]);

    // ---- distributed numerator partial: steps s in [s0+1, s0+L] ----
    {
        float np = 0.f;
        int   mc = 0;
        if (lane < L) {
            int s  = s0 + 1 + lane;
            int m  = mk_b[s];
            mc = m;
            int t  = tg_b[s];
            int tp = tg_b[s - 1];
            float v = trans[tp * NT + t] + em_b[(size_t)s * NT + t];
            np = m ? v : 0.f;
        }
        if (c == 0 && lane == 0) {
            int t0 = tg_b[0];
            np += start_tr[t0] + em_b[t0];
            mc += mk_b[0];
        }
#pragma unroll
        for (int d = 32; d; d >>= 1) {
            np += __shfl_xor(np, d);
            mc += __shfl_xor(mc, d);
        }
        if (lane == 0) {
            score_part[b * PCH + c] = np;
            mcnt_part[b * PCH + c]  = mc;
        }
    }

    // Permuted A: Af[mt][kk] slot (h,j) = Es[mt*32+ml][r], Es = E^T * 2^-7,
    // r = 32*(kk>>1) + 16*(kk&1) + (j&3) + 8*(j>>2) + 4h
    bf16x8 Af[2][4];
#pragma unroll
    for (int mt = 0; mt < 2; ++mt) {
        int m = mt * 32 + ml;
#pragma unroll
        for (int kk = 0; kk < 4; ++kk) {
            bf16x8 f;
#pragma unroll
            for (int j = 0; j < 8; ++j) {
                int r = 32 * (kk >> 1) + 16 * (kk & 1) + (j & 3) + 8 * (j >> 2) + 4 * h;
                f[j] = bf16_trunc(__expf(trans[r * NT + m]) * 0.0078125f);
            }
            Af[mt][kk] = f;
        }
    }

    // B := identity (permuted-B register convention)
    union BU { unsigned u[4]; bf16x8 v; };
    BU Bv[4][2];
#pragma unroll
    for (int kk = 0; kk < 4; ++kk)
#pragma unroll
        for (int nt = 0; nt < 2; ++nt) {
            int n = nt * 32 + ml;
#pragma unroll
            for (int d = 0; d < 4; ++d) {
                int j0 = 2 * d;
                int r0 = 32 * (kk >> 1) + 16 * (kk & 1) + (j0 & 3) + 8 * (j0 >> 2) + 4 * h;
                unsigned lo = (r0     == n) ? 0x3f80u : 0u;
                unsigned hi = (r0 + 1 == n) ? 0x3f80u : 0u;
                Bv[kk][nt].u[d] = lo | (hi << 16);
            }
        }

    __syncthreads();  // w_lds drained (single wave: waitcnt only)

    const f32x16 zf = {};

    for (int s = 0; s < L; ++s) {
        f32x4 wq[4][2];
#pragma unroll
        for (int kk = 0; kk < 4; ++kk) {
            int base = 32 * (kk >> 1) + 16 * (kk & 1) + 4 * h;
            wq[kk][0] = *(const f32x4*)&w_lds[s][base];
            wq[kk][1] = *(const f32x4*)&w_lds[s][base + 8];
        }

        f32x16 acc[2][2];
#pragma unroll
        for (int mt = 0; mt < 2; ++mt)
#pragma unroll
            for (int nt = 0; nt < 2; ++nt) {
                f32x16 a = __builtin_amdgcn_mfma_f32_32x32x16_bf16(Af[mt][0], Bv[0][nt].v, zf, 0, 0, 0);
                a = __builtin_amdgcn_mfma_f32_32x32x16_bf16(Af[mt][1], Bv[1][nt].v, a, 0, 0, 0);
                a = __builtin_amdgcn_mfma_f32_32x32x16_bf16(Af[mt][2], Bv[2][nt].v, a, 0, 0, 0);
                a = __builtin_amdgcn_mfma_f32_32x32x16_bf16(Af[mt][3], Bv[3][nt].v, a, 0, 0, 0);
                acc[mt][nt] = a;
            }

        // Repack: B-slot (kk,nt,d) <- w[r]*C[r][n] pairs, packed bf16 cvt.
#pragma unroll
        for (int kk = 0; kk < 4; ++kk) {
            const int mt_s = kk >> 1, qo = 8 * (kk & 1);
#pragma unroll
            for (int nt = 0; nt < 2; ++nt) {
#pragma unroll
                for (int d = 0; d < 4; ++d) {
                    int j0 = 2 * d;
                    float v0 = acc[mt_s][nt][qo + j0]     * wq[kk][d >> 1][2 * (d & 1)];
                    float v1 = acc[mt_s][nt][qo + j0 + 1] * wq[kk][d >> 1][2 * (d & 1) + 1];
                    Bv[kk][nt].u[d] = pack_bf16_rn(v0, v1);
                }
            }
        }
    }

    // Transpose through LDS (once) -> mats[n][k] = M[k][n]
    __threadfence_block();
#pragma unroll
    for (int kk = 0; kk < 4; ++kk)
#pragma unroll
        for (int nt = 0; nt < 2; ++nt) {
            int n = nt * 32 + ml;
#pragma unroll
            for (int d = 0; d < 4; ++d) {
                int j0 = 2 * d;
                int r0 = 32 * (kk >> 1) + 16 * (kk & 1) + (j0 & 3) + 8 * (j0 >> 2) + 4 * h;
                *(unsigned*)&ldsT[n * PITCH + r0] = Bv[kk][nt].u[d];
            }
        }
    __threadfence_block();

    unsigned short* outp = mats + ((size_t)(b * PCH + c)) * 4096;
    for (int it = 0; it < 8; ++it) {
        int o = it * 512 + lane * 8;
        int n = o >> 6, k = o & 63;
        const uint2* p = (const uint2*)(ldsT + n * PITCH + k);
        uint2 x = p[0], y = p[1];
        uint4 q4; q4.x = x.x; q4.y = x.y; q4.z = y.x; q4.w = y.y;
        *(uint4*)(outp + o) = q4;
    }

    // ---- release + elect last block of this batch (single wave) ----
    __threadfence();
    unsigned old = 0;
    if (lane == 0) old = atomicAdd(&done[b], 1u);
    old = __shfl(old, 0);
    if (old != PCH - 1) return;
    __threadfence();   // acquire: all 8 chunk writes for batch b now visible

    // ================= combine (elected block's single wave) ===============
    const int j = lane;
    const unsigned short* mb = mats + (size_t)b * PCH * 4096;

    float sp = (j < PCH) ? score_part[b * PCH + j] : 0.f;
    int   mp = (j < PCH) ? mcnt_part[b * PCH + j] : 0;

    float r = __expf(end_tr[j]);
    MEMBAR(); r_lds[j] = r; MEMBAR();
    int X = 0;

    uint4 buf[2][8];
#pragma unroll
    for (int u = 0; u < 8; ++u)
        buf[0][u] = *(const uint4*)(mb + (size_t)(PCH - 1) * 4096 + j * 64 + u * 8);

#pragma unroll
    for (int d = 32; d; d >>= 1) {
        sp += __shfl_xor(sp, d);
        mp += __shfl_xor(mp, d);
    }
    float score_num = sp + end_tr[tg_b[mp - 1]];

#pragma unroll
    for (int cc = PCH - 1; cc >= 0; --cc) {
        const int slot = (PCH - 1 - cc) & 1;
        if (cc > 0) {
#pragma unroll
            for (int u = 0; u < 8; ++u)
                buf[slot ^ 1][u] = *(const uint4*)(mb + (size_t)(cc - 1) * 4096 + j * 64 + u * 8);
        }
        float a0 = 0.f, a1 = 0.f, a2 = 0.f, a3 = 0.f;
#pragma unroll
        for (int u = 0; u < 8; ++u) {
            uint4 q = buf[slot][u];
            f32x4 ra = *(const f32x4*)&r_lds[u * 8];
            f32x4 rb = *(const f32x4*)&r_lds[u * 8 + 4];
            a0 = fmaf(ra[0], __uint_as_float(q.x << 16),         a0);
            a1 = fmaf(ra[1], __uint_as_float(q.x & 0xffff0000u), a1);
            a2 = fmaf(ra[2], __uint_as_float(q.y << 16),         a2);
            a3 = fmaf(ra[3], __uint_as_float(q.y & 0xffff0000u), a3);
            a0 = fmaf(rb[0], __uint_as_float(q.z << 16),         a0);
            a1 = fmaf(rb[1], __uint_as_float(q.z & 0xffff0000u), a1);
            a2 = fmaf(rb[2], __uint_as_float(q.w << 16),         a2);
            a3 = fmaf(rb[3], __uint_as_float(q.w & 0xffff0000u), a3);
        }
        float rn = (a0 + a1) + (a2 + a3);
        unsigned eb = (__builtin_amdgcn_readfirstlane((int)__float_as_uint(rn)) >> 23) & 0xffu;
        r = rn * __uint_as_float((254u - eb) << 23);   // * 2^(127-eb)
        X += (int)eb - 127;
        MEMBAR();
        r_lds[j] = r;     // in-order LDS pipe within the wave
        MEMBAR();
    }

    float u0 = __expf(start_tr[j] + em_b[j]);
    float v = r * u0;
#pragma unroll
    for (int d = 32; d; d >>= 1) v += __shfl_xor(v, d);

    if (j == 0) {
        float denom = __logf(v) + (float)(X + 7 * (SEQ - 1)) * 0.6931471805599453f;
        float llh = denom - score_num;
        atomicAdd(&ws_head[0], llh * (1.0f / BATCH));
        __threadfence();
        unsigned oldc = atomicAdd((unsigned*)ws_head + 1, 1u);
        if (oldc == BATCH - 1) {
            __threadfence();
            out[0] = atomicAdd(&ws_head[0], 0.0f);
        }
    }
}

extern "C" void kernel_launch(void* const* d_in, const int* in_sizes, int n_in,
                              void* d_out, int out_size, void* d_ws, size_t ws_size,
                              hipStream_t stream) {
    const float* emissions = (const float*)d_in[0];
    const int*   tags      = (const int*)d_in[1];
    const int*   mask      = (const int*)d_in[2];
    const float* start_tr  = (const float*)d_in[3];
    const float* end_tr    = (const float*)d_in[4];
    const float* trans     = (const float*)d_in[5];

    float*    ws_head    = (float*)d_ws;                           // 8 B
    unsigned* done       = (unsigned*)((char*)d_ws + 64);          // 1 KB
    float*    score_part = (float*)((char*)d_ws + 4096);           // 8 KB
    int*      mcnt_part  = (int*)((char*)d_ws + 12288);            // 8 KB
    unsigned short* mats = (unsigned short*)((char*)d_ws + 32768); // 16 MB

    hipMemsetAsync(d_ws, 0, 4096, stream);   // zero ws_head + done counters
    crf_fused_kernel<<<dim3(PCH, BATCH), 64, 0, stream>>>(
        emissions, tags, mask, start_tr, end_tr, trans,
        mats, ws_head, done, score_part, mcnt_part, (float*)d_out);
}

// Round 8
// 162.547 us; speedup vs baseline: 1.8505x; 1.4364x over previous
//
#include <hip/hip_runtime.h>
#include <hip/hip_bf16.h>

#define BATCH 256
#define SEQ   512
#define NT    64
#define NW    8     // waves per block = chunks per sequence
#define CLEN  64    // steps per chunk (last chunk: 63)

typedef short    bf16x8 __attribute__((ext_vector_type(8)));
typedef float    f32x16 __attribute__((ext_vector_type(16)));
typedef float    f32x4  __attribute__((ext_vector_type(4)));
typedef _Float16 h4     __attribute__((ext_vector_type(4)));

#define MEMBAR() __asm__ __volatile__("" ::: "memory")

static __device__ __forceinline__ short bf16_trunc(float v) {
    return (short)(__float_as_uint(v) >> 16);
}
static __device__ __forceinline__ unsigned pack_bf16_rn(float lo, float hi) {
    float2 f; f.x = lo; f.y = hi;
    __hip_bfloat162 hh = __float22bfloat162_rn(f);   // v_cvt_pk_bf16_f32
    unsigned u; __builtin_memcpy(&u, &hh, 4);
    return u;
}

// ---------------------------------------------------------------------------
// One block = one batch = 8 waves. Wave c computes chunk c's 64x64 product
// in registers (proven r4 loop: 16 MFMA/step, C accs feed next B, row perm
// rho(h,j)=(j&3)+8*(j>>2)+4h pre-folded into A). Chunk matrices never leave
// the CU: written (bf16, XOR-swizzled) into LDS, combined by wave 0.
// No device fences in the hot path -> no cross-XCD visibility cost.
// ---------------------------------------------------------------------------
__global__ __launch_bounds__(512, 2) void crf_fused_kernel(
    const float* __restrict__ emissions,   // (B,S,T)
    const int*   __restrict__ tags,        // (B,S)
    const int*   __restrict__ mask,        // (B,S)
    const float* __restrict__ start_tr,    // (T)
    const float* __restrict__ end_tr,      // (T)
    const float* __restrict__ trans,       // (T,T)
    float* __restrict__ ws_head,           // [0]=sum, [1]=cnt (pre-zeroed)
    float* __restrict__ out)
{
    __shared__ __align__(16) unsigned char smem[NW * 8192];  // 64 KB exactly

    const int b    = blockIdx.x;
    const int tid  = threadIdx.x;
    const int lane = tid & 63;
    const int c    = tid >> 6;      // wave index == chunk index
    const int h    = lane >> 5;
    const int ml   = lane & 31;

    const int s0 = c * CLEN;
    int L = (SEQ - 1) - s0; if (L > CLEN) L = CLEN;

    const float* em_b = emissions + (size_t)b * SEQ * NT;
    const int*   tg_b = tags + b * SEQ;
    const int*   mk_b = mask + b * SEQ;

    // stage w = exp(emissions) for this wave's steps into its OWN 8 KB slice
    _Float16* wk = (_Float16*)(smem + c * 8192);
    for (int s = 0; s < L; ++s)
        wk[s * NT + lane] = (_Float16)__expf(em_b[(size_t)(s0 + 1 + s) * NT + lane]);

    // wave 0 also computes the full gold-path numerator (it is the combine wave)
    float score_num = 0.f;
    if (c == 0) {
        float part = 0.f;
        int mcount = 0;
        for (int s = lane; s < SEQ; s += 64) {
            int m = mk_b[s];
            mcount += m;
            int t = tg_b[s];
            if (s == 0) {
                part += start_tr[t] + em_b[t];
            } else {
                int tp = tg_b[s - 1];
                float v = trans[tp * NT + t] + em_b[(size_t)s * NT + t];
                part += m ? v : 0.f;
            }
        }
#pragma unroll
        for (int d = 32; d; d >>= 1) {
            part   += __shfl_xor(part, d);
            mcount += __shfl_xor(mcount, d);
        }
        score_num = part + end_tr[tg_b[mcount - 1]];
    }

    // Permuted A: Af[mt][kk] slot (h,j) = Es[mt*32+ml][r], Es = E^T * 2^-7,
    // r = 32*(kk>>1) + 16*(kk&1) + (j&3) + 8*(j>>2) + 4h   (proven r4-r7)
    bf16x8 Af[2][4];
#pragma unroll
    for (int mt = 0; mt < 2; ++mt) {
        int m = mt * 32 + ml;
#pragma unroll
        for (int kk = 0; kk < 4; ++kk) {
            bf16x8 f;
#pragma unroll
            for (int j = 0; j < 8; ++j) {
                int r = 32 * (kk >> 1) + 16 * (kk & 1) + (j & 3) + 8 * (j >> 2) + 4 * h;
                f[j] = bf16_trunc(__expf(trans[r * NT + m]) * 0.0078125f);
            }
            Af[mt][kk] = f;
        }
    }

    // B := identity (permuted-B register convention)
    union BU { unsigned u[4]; bf16x8 v; };
    BU Bv[4][2];
#pragma unroll
    for (int kk = 0; kk < 4; ++kk)
#pragma unroll
        for (int nt = 0; nt < 2; ++nt) {
            int n = nt * 32 + ml;
#pragma unroll
            for (int d = 0; d < 4; ++d) {
                int j0 = 2 * d;
                int r0 = 32 * (kk >> 1) + 16 * (kk & 1) + (j0 & 3) + 8 * (j0 >> 2) + 4 * h;
                unsigned lo = (r0     == n) ? 0x3f80u : 0u;
                unsigned hi = (r0 + 1 == n) ? 0x3f80u : 0u;
                Bv[kk][nt].u[d] = lo | (hi << 16);
            }
        }

    const f32x16 zf = {};

    // main loop: reads only this wave's own LDS slice -> no barrier needed
    for (int s = 0; s < L; ++s) {
        h4 wa[4], wb[4];
#pragma unroll
        for (int kk = 0; kk < 4; ++kk) {
            int base = s * NT + 32 * (kk >> 1) + 16 * (kk & 1) + 4 * h;
            wa[kk] = *(const h4*)&wk[base];
            wb[kk] = *(const h4*)&wk[base + 8];
        }

        f32x16 acc[2][2];
#pragma unroll
        for (int mt = 0; mt < 2; ++mt)
#pragma unroll
            for (int nt = 0; nt < 2; ++nt) {
                f32x16 a = __builtin_amdgcn_mfma_f32_32x32x16_bf16(Af[mt][0], Bv[0][nt].v, zf, 0, 0, 0);
                a = __builtin_amdgcn_mfma_f32_32x32x16_bf16(Af[mt][1], Bv[1][nt].v, a, 0, 0, 0);
                a = __builtin_amdgcn_mfma_f32_32x32x16_bf16(Af[mt][2], Bv[2][nt].v, a, 0, 0, 0);
                a = __builtin_amdgcn_mfma_f32_32x32x16_bf16(Af[mt][3], Bv[3][nt].v, a, 0, 0, 0);
                acc[mt][nt] = a;
            }

        // Repack: B-slot (kk,nt,d) <- w[r]*C[r][n] pairs, packed bf16 cvt.
#pragma unroll
        for (int kk = 0; kk < 4; ++kk) {
            const int mt_s = kk >> 1, qo = 8 * (kk & 1);
#pragma unroll
            for (int nt = 0; nt < 2; ++nt) {
#pragma unroll
                for (int d = 0; d < 4; ++d) {
                    int j0 = 2 * d;
                    float w0 = (float)((d < 2) ? wa[kk][2 * (d & 1)]     : wb[kk][2 * (d & 1)]);
                    float w1 = (float)((d < 2) ? wa[kk][2 * (d & 1) + 1] : wb[kk][2 * (d & 1) + 1]);
                    float v0 = acc[mt_s][nt][qo + j0]     * w0;
                    float v1 = acc[mt_s][nt][qo + j0 + 1] * w1;
                    Bv[kk][nt].u[d] = pack_bf16_rn(v0, v1);
                }
            }
        }
    }

    // write chunk matrix into OWN slice (w region dead), XOR-swizzled:
    // logical [n][k] at half-index n*64 + (k ^ ((n&7)<<3))
    unsigned short* mt_ = (unsigned short*)(smem + c * 8192);
    MEMBAR();
#pragma unroll
    for (int kk = 0; kk < 4; ++kk)
#pragma unroll
        for (int nt = 0; nt < 2; ++nt) {
            int n = nt * 32 + ml;
#pragma unroll
            for (int d = 0; d < 4; ++d) {
                int j0 = 2 * d;
                int r0 = 32 * (kk >> 1) + 16 * (kk & 1) + (j0 & 3) + 8 * (j0 >> 2) + 4 * h;
                *(unsigned*)&mt_[n * 64 + (r0 ^ ((n & 7) << 3))] = Bv[kk][nt].u[d];
            }
        }

    __syncthreads();   // all 8 chunk matrices visible block-wide
    if (c != 0) return;

    // ================= combine (wave 0, all from LDS) =================
    const int j = lane;
    float* r_lds = (float*)(smem + 7 * 8192);  // overlays M_7 rows 0-1 (dead after its preload)
    float r = __expf(end_tr[j]);
    int X = 0;

#pragma unroll
    for (int cc = NW - 1; cc >= 0; --cc) {
        const unsigned short* mrow = (const unsigned short*)(smem + cc * 8192) + j * 64;
        uint4 q[8];
#pragma unroll
        for (int u = 0; u < 8; ++u)
            q[u] = *(const uint4*)&mrow[(u ^ (j & 7)) << 3];   // de-swizzle
        MEMBAR();
        r_lds[j] = r;          // DS pipe in-order: issued after the row reads
        MEMBAR();

        float a0 = 0.f, a1 = 0.f, a2 = 0.f, a3 = 0.f;
#pragma unroll
        for (int u = 0; u < 8; ++u) {
            uint4 qq = q[u];
            f32x4 ra = *(const f32x4*)&r_lds[u * 8];
            f32x4 rb = *(const f32x4*)&r_lds[u * 8 + 4];
            a0 = fmaf(ra[0], __uint_as_float(qq.x << 16),         a0);
            a1 = fmaf(ra[1], __uint_as_float(qq.x & 0xffff0000u), a1);
            a2 = fmaf(ra[2], __uint_as_float(qq.y << 16),         a2);
            a3 = fmaf(ra[3], __uint_as_float(qq.y & 0xffff0000u), a3);
            a0 = fmaf(rb[0], __uint_as_float(qq.z << 16),         a0);
            a1 = fmaf(rb[1], __uint_as_float(qq.z & 0xffff0000u), a1);
            a2 = fmaf(rb[2], __uint_as_float(qq.w << 16),         a2);
            a3 = fmaf(rb[3], __uint_as_float(qq.w & 0xffff0000u), a3);
        }
        float rn = (a0 + a1) + (a2 + a3);
        unsigned eb = (__builtin_amdgcn_readfirstlane((int)__float_as_uint(rn)) >> 23) & 0xffu;
        r = rn * __uint_as_float((254u - eb) << 23);   // * 2^(127-eb)
        X += (int)eb - 127;
    }

    float u0 = __expf(start_tr[j] + em_b[j]);
    float v = r * u0;
#pragma unroll
    for (int d = 32; d; d >>= 1) v += __shfl_xor(v, d);

    if (j == 0) {
        float denom = __logf(v) + (float)(X + 7 * (SEQ - 1)) * 0.6931471805599453f;
        float llh = denom - score_num;
        atomicAdd(&ws_head[0], llh * (1.0f / BATCH));
        __threadfence();
        unsigned oldc = atomicAdd((unsigned*)ws_head + 1, 1u);
        if (oldc == BATCH - 1) {
            __threadfence();
            out[0] = atomicAdd(&ws_head[0], 0.0f);
        }
    }
}

extern "C" void kernel_launch(void* const* d_in, const int* in_sizes, int n_in,
                              void* d_out, int out_size, void* d_ws, size_t ws_size,
                              hipStream_t stream) {
    const float* emissions = (const float*)d_in[0];
    const int*   tags      = (const int*)d_in[1];
    const int*   mask      = (const int*)d_in[2];
    const float* start_tr  = (const float*)d_in[3];
    const float* end_tr    = (const float*)d_in[4];
    const float* trans     = (const float*)d_in[5];

    float* ws_head = (float*)d_ws;   // [0]=sum, [1]=cnt

    hipMemsetAsync(d_ws, 0, 64, stream);
    crf_fused_kernel<<<BATCH, 512, 0, stream>>>(
        emissions, tags, mask, start_tr, end_tr, trans,
        ws_head, (float*)d_out);
}